// Round 1
// baseline (428.985 us; speedup 1.0000x reference)
//
#include <hip/hip_runtime.h>

// SwinV2 window attention, fused 3-stage fp16-MFMA pipeline.
// ws layout (bytes): [0,128K) biasfrag f32 | [128K,512K) w_t fp16[768][256]
//   | [512K,640K) p_t fp16[256][256] | @1M qbuf 64M | kbuf 64M | vtbuf 64M
// total ~193 MiB of d_ws.

typedef _Float16 f16;
typedef _Float16 f16x4 __attribute__((ext_vector_type(4)));
typedef _Float16 f16x8 __attribute__((ext_vector_type(8)));
typedef float f32x4 __attribute__((ext_vector_type(4)));

#define LOG100 4.6051701859880914f
#define EPS_L2 1.55e-5f

__device__ __forceinline__ int seg2(int p) { return (p >= 248) + (p >= 252); }

// ---------------- prep: CPB bias (in MFMA C-fragment order) + weight transpose/convert
__global__ __launch_bounds__(512) void k_prep(
    const float* __restrict__ cpb_w1, const float* __restrict__ cpb_b1,
    const float* __restrict__ cpb_w2, const float* __restrict__ qkv_w,
    const float* __restrict__ proj_w,
    float* __restrict__ biasfrag, f16* __restrict__ w_t, f16* __restrict__ p_t)
{
    __shared__ float cpb[225 * 8];
    int tid = threadIdx.x;
    if (blockIdx.x == 0) {
        if (tid < 225) {
            int a = tid / 15, b2 = tid % 15;
            float xa = (float)(a - 7) * (8.0f / 7.0f);
            float xb = (float)(b2 - 7) * (8.0f / 7.0f);
            float t0 = (xa < 0.f ? -1.f : 1.f) * log2f(1.0f + fabsf(xa)) * (1.0f / 3.0f);
            float t1 = (xb < 0.f ? -1.f : 1.f) * log2f(1.0f + fabsf(xb)) * (1.0f / 3.0f);
            float acc[8] = {0.f, 0.f, 0.f, 0.f, 0.f, 0.f, 0.f, 0.f};
            for (int j = 0; j < 512; ++j) {
                float hh = t0 * cpb_w1[j] + t1 * cpb_w1[512 + j] + cpb_b1[j];
                hh = fmaxf(hh, 0.0f);
                #pragma unroll
                for (int h = 0; h < 8; ++h) acc[h] += hh * cpb_w2[j * 8 + h];
            }
            #pragma unroll
            for (int h = 0; h < 8; ++h) cpb[tid * 8 + h] = acc[h];
        }
        __syncthreads();
        // biasfrag flat index f = (((h*4+mt)*4+nt)*64+lane)*4 + r
        for (int f = tid; f < 32768; f += 512) {
            int r = f & 3, lane = (f >> 2) & 63, nt = (f >> 8) & 3, mt = (f >> 10) & 3, h = (f >> 12) & 7;
            int q = mt * 16 + ((lane >> 4) << 2) + r;
            int k = nt * 16 + (lane & 15);
            int idx = ((q >> 3) - (k >> 3) + 7) * 15 + ((q & 7) - (k & 7) + 7);
            float c = cpb[idx * 8 + h];
            biasfrag[f] = 16.0f / (1.0f + expf(-c));
        }
    } else {
        int base = (blockIdx.x - 1) * 512 + tid;
        const int stride = 128 * 512;
        for (int i = base; i < 768 * 256; i += stride) {
            int n = i >> 8, k = i & 255;
            w_t[i] = (f16)qkv_w[k * 768 + n];     // w_t[n][k] = W[k][n]
        }
        for (int i = base; i < 256 * 256; i += stride) {
            int n = i >> 8, k = i & 255;
            p_t[i] = (f16)proj_w[k * 256 + n];
        }
    }
}

// ---------------- K1: qkv GEMM + bias + roll(-4) + window partition + l2norm(q,k) + q*logit_scale
// qbuf/kbuf: [b*1024+win][64 pos][256 ch] fp16 ; vtbuf: [(b*1024+win)*8+h][32 u][64 key] fp16
__global__ __launch_bounds__(512, 2) void k_qkv(
    const float* __restrict__ x, const f16* __restrict__ w_t,
    const float* __restrict__ q_bias, const float* __restrict__ v_bias,
    const float* __restrict__ scale,
    f16* __restrict__ qbuf, f16* __restrict__ kbuf, f16* __restrict__ vtbuf)
{
    __shared__ f16 Al[128 * 256];            // 64 KiB, rows XOR-swizzled (T2)
    const int tid = threadIdx.x;
    const int lane = tid & 63;
    const int wv = tid >> 6;                 // 8 waves: 2(m) x 4(n)
    const int wm = wv >> 2;
    const int wn = wv & 3;
    const long mbase = (long)blockIdx.x * 128;

    // stage A (128 x 256 fp32 -> fp16), one full row (1 KiB) per wave per rep
    #pragma unroll
    for (int rep = 0; rep < 16; ++rep) {
        int row = rep * 8 + wv;
        int k4 = lane * 4;
        float4 v = *reinterpret_cast<const float4*>(x + (mbase + row) * 256 + k4);
        f16x4 hv = { (f16)v.x, (f16)v.y, (f16)v.z, (f16)v.w };
        int byte = (row * 512 + k4 * 2) ^ ((row & 7) << 4);
        *reinterpret_cast<f16x4*>(reinterpret_cast<char*>(Al) + byte) = hv;
    }
    __syncthreads();

    const f32x4 fzero = {0.f, 0.f, 0.f, 0.f};
    #pragma unroll 1
    for (int np = 0; np < 6; ++np) {
        const int nbase = np * 128;
        f32x4 acc[4][2];
        #pragma unroll
        for (int mt = 0; mt < 4; ++mt) { acc[mt][0] = fzero; acc[mt][1] = fzero; }

        #pragma unroll
        for (int ks = 0; ks < 8; ++ks) {
            f16x8 a[4], b[2];
            #pragma unroll
            for (int mt = 0; mt < 4; ++mt) {
                int row = wm * 64 + mt * 16 + (lane & 15);
                int byte = (row * 512 + ks * 64 + ((lane >> 4) << 4)) ^ ((row & 7) << 4);
                a[mt] = *reinterpret_cast<const f16x8*>(reinterpret_cast<const char*>(Al) + byte);
            }
            #pragma unroll
            for (int nt = 0; nt < 2; ++nt) {
                int nrow = nbase + wn * 32 + nt * 16 + (lane & 15);
                b[nt] = *reinterpret_cast<const f16x8*>(w_t + nrow * 256 + ks * 32 + ((lane >> 4) << 3));
            }
            #pragma unroll
            for (int mt = 0; mt < 4; ++mt)
                #pragma unroll
                for (int nt = 0; nt < 2; ++nt)
                    acc[mt][nt] = __builtin_amdgcn_mfma_f32_16x16x32_f16(a[mt], b[nt], acc[mt][nt], 0, 0, 0);
        }

        const int which = nbase >> 8;                  // 0=q 1=k 2=v
        const int chbase = (nbase & 255) + wn * 32;    // 32-aligned -> one head per wave slice
        const int c0 = chbase + (lane & 15);
        float b0 = 0.f, b1 = 0.f;
        if (which == 0) { b0 = q_bias[c0]; b1 = q_bias[c0 + 16]; }
        if (which == 2) { b0 = v_bias[c0]; b1 = v_bias[c0 + 16]; }
        #pragma unroll
        for (int mt = 0; mt < 4; ++mt)
            #pragma unroll
            for (int r = 0; r < 4; ++r) { acc[mt][0][r] += b0; acc[mt][1][r] += b1; }

        if (which < 2) {
            float ls = 1.0f;
            if (which == 0) ls = expf(fminf(scale[chbase >> 5], LOG100));
            f16* dst = (which == 0) ? qbuf : kbuf;
            #pragma unroll
            for (int mt = 0; mt < 4; ++mt) {
                #pragma unroll
                for (int r = 0; r < 4; ++r) {
                    float s = acc[mt][0][r] * acc[mt][0][r] + acc[mt][1][r] * acc[mt][1][r];
                    s += __shfl_xor(s, 1); s += __shfl_xor(s, 2);
                    s += __shfl_xor(s, 4); s += __shfl_xor(s, 8);
                    float inv = ls / sqrtf(fmaxf(s, EPS_L2));
                    long m = mbase + wm * 64 + mt * 16 + ((lane >> 4) << 2) + r;
                    int bb = (int)(m >> 16);
                    int ij = (int)(m & 65535);
                    int ip = ((ij >> 8) + 252) & 255;       // roll(-4)
                    int jp = ((ij & 255) + 252) & 255;
                    int win = ((ip >> 3) << 5) | (jp >> 3);
                    int qq  = ((ip & 7) << 3) | (jp & 7);
                    long base = (((long)((bb << 10) | win)) * 64 + qq) * 256;
                    dst[base + c0]      = (f16)(acc[mt][0][r] * inv);
                    dst[base + c0 + 16] = (f16)(acc[mt][1][r] * inv);
                }
            }
        } else {
            const int h = chbase >> 5;
            #pragma unroll
            for (int mt = 0; mt < 4; ++mt) {
                long m0 = mbase + wm * 64 + mt * 16 + ((lane >> 4) << 2);
                int bb = (int)(m0 >> 16);
                int ij = (int)(m0 & 65535);
                int ip  = ((ij >> 8) + 252) & 255;
                int jp0 = ((ij & 255) + 252) & 255;
                int win = ((ip >> 3) << 5) | (jp0 >> 3);
                int k0  = ((ip & 7) << 3) | (jp0 & 7);     // 4-aligned; 4 regs = 4 consecutive keys
                long vbase = ((long)((bb << 10) | win) * 8 + h) * 32;
                #pragma unroll
                for (int nt = 0; nt < 2; ++nt) {
                    int u = (lane & 15) + nt * 16;
                    f16x4 pk = { (f16)acc[mt][nt][0], (f16)acc[mt][nt][1],
                                 (f16)acc[mt][nt][2], (f16)acc[mt][nt][3] };
                    *reinterpret_cast<f16x4*>(vtbuf + (vbase + u) * 64 + k0) = pk;
                }
            }
        }
    }
}

// ---------------- K2: per-window attention (+CPB bias +shift mask +softmax) fused with proj
__global__ __launch_bounds__(512, 2) void k_attn_proj(
    const f16* __restrict__ qbuf, const f16* __restrict__ kbuf,
    const f16* __restrict__ vtbuf, const float* __restrict__ biasfrag,
    const f16* __restrict__ p_t, const float* __restrict__ proj_b,
    float* __restrict__ out)
{
    __shared__ char LDSRAW[65536];           // 8 x 8KiB P buffers; first 32KiB reused as out_tile
    const int tid = threadIdx.x;
    const int lane = tid & 63;
    const int h = tid >> 6;                  // wave == head
    const int bw = blockIdx.x;               // b*1024 + win
    const int win = bw & 1023;
    const int wh = win >> 5, ww = win & 31;
    const f32x4 fzero = {0.f, 0.f, 0.f, 0.f};

    const f16* qp = qbuf + (long)bw * 16384 + h * 32;
    const f16* kp = kbuf + (long)bw * 16384 + h * 32;
    const f16* vp = vtbuf + ((long)bw * 8 + h) * 2048;

    f16x8 qa[4], kb[4], vf[2][2];
    #pragma unroll
    for (int t = 0; t < 4; ++t) {
        qa[t] = *reinterpret_cast<const f16x8*>(qp + (t * 16 + (lane & 15)) * 256 + ((lane >> 4) << 3));
        kb[t] = *reinterpret_cast<const f16x8*>(kp + (t * 16 + (lane & 15)) * 256 + ((lane >> 4) << 3));
    }
    #pragma unroll
    for (int nt = 0; nt < 2; ++nt)
        #pragma unroll
        for (int ks = 0; ks < 2; ++ks)
            vf[nt][ks] = *reinterpret_cast<const f16x8*>(vp + (nt * 16 + (lane & 15)) * 64 + ks * 32 + ((lane >> 4) << 3));

    // S = (q*ls) . k^T
    f32x4 s[4][4];
    #pragma unroll
    for (int mt = 0; mt < 4; ++mt)
        #pragma unroll
        for (int nt = 0; nt < 4; ++nt)
            s[mt][nt] = __builtin_amdgcn_mfma_f32_16x16x32_f16(qa[mt], kb[nt], fzero, 0, 0, 0);

    const f32x4* bf = reinterpret_cast<const f32x4*>(biasfrag);
    #pragma unroll
    for (int mt = 0; mt < 4; ++mt)
        #pragma unroll
        for (int nt = 0; nt < 4; ++nt)
            s[mt][nt] += bf[((h * 4 + mt) * 4 + nt) * 64 + lane];

    if (wh == 31 || ww == 31) {              // shift mask, boundary windows only
        #pragma unroll
        for (int mt = 0; mt < 4; ++mt)
            #pragma unroll
            for (int r = 0; r < 4; ++r) {
                int q = mt * 16 + ((lane >> 4) << 2) + r;
                int lq = seg2(wh * 8 + (q >> 3)) * 3 + seg2(ww * 8 + (q & 7));
                #pragma unroll
                for (int nt = 0; nt < 4; ++nt) {
                    int k = nt * 16 + (lane & 15);
                    int lk = seg2(wh * 8 + (k >> 3)) * 3 + seg2(ww * 8 + (k & 7));
                    if (lq != lk) s[mt][nt][r] -= 100.0f;
                }
            }
    }

    // softmax over k: each row lives in one 16-lane group (4 frag cols x 16 lanes)
    float inv_[4][4];
    #pragma unroll
    for (int mt = 0; mt < 4; ++mt)
        #pragma unroll
        for (int r = 0; r < 4; ++r) {
            float mx = fmaxf(fmaxf(s[mt][0][r], s[mt][1][r]), fmaxf(s[mt][2][r], s[mt][3][r]));
            mx = fmaxf(mx, __shfl_xor(mx, 1));
            mx = fmaxf(mx, __shfl_xor(mx, 2));
            mx = fmaxf(mx, __shfl_xor(mx, 4));
            mx = fmaxf(mx, __shfl_xor(mx, 8));
            float sm = 0.f;
            #pragma unroll
            for (int nt = 0; nt < 4; ++nt) {
                float e = __expf(s[mt][nt][r] - mx);
                s[mt][nt][r] = e;
                sm += e;
            }
            sm += __shfl_xor(sm, 1); sm += __shfl_xor(sm, 2);
            sm += __shfl_xor(sm, 4); sm += __shfl_xor(sm, 8);
            inv_[mt][r] = 1.0f / sm;
        }

    // P (unnormalized exp) -> per-head LDS, fp16, XOR-swizzled rows of 128 B
    char* Pb = LDSRAW + (h << 13);
    #pragma unroll
    for (int mt = 0; mt < 4; ++mt)
        #pragma unroll
        for (int nt = 0; nt < 4; ++nt)
            #pragma unroll
            for (int r = 0; r < 4; ++r) {
                int q = mt * 16 + ((lane >> 4) << 2) + r;
                int k = nt * 16 + (lane & 15);
                *reinterpret_cast<f16*>(Pb + ((q * 128 + k * 2) ^ ((q & 7) << 4))) = (f16)s[mt][nt][r];
            }
    __syncthreads();

    // O = P @ V  (normalization deferred to epilogue)
    f32x4 o[4][2];
    #pragma unroll
    for (int mt = 0; mt < 4; ++mt) {
        int q = mt * 16 + (lane & 15);
        int swz = (q & 7) << 4;
        f16x8 pa0 = *reinterpret_cast<const f16x8*>(Pb + ((q * 128 + ((lane >> 4) << 4)) ^ swz));
        f16x8 pa1 = *reinterpret_cast<const f16x8*>(Pb + ((q * 128 + 64 + ((lane >> 4) << 4)) ^ swz));
        #pragma unroll
        for (int nt = 0; nt < 2; ++nt) {
            f32x4 t = __builtin_amdgcn_mfma_f32_16x16x32_f16(pa0, vf[nt][0], fzero, 0, 0, 0);
            o[mt][nt] = __builtin_amdgcn_mfma_f32_16x16x32_f16(pa1, vf[nt][1], t, 0, 0, 0);
        }
    }
    __syncthreads();   // all PV reads complete before out_tile overwrites P region

    // out_tile[64][256] fp16 (softmax-normalized), XOR-swizzled rows of 512 B
    #pragma unroll
    for (int mt = 0; mt < 4; ++mt)
        #pragma unroll
        for (int r = 0; r < 4; ++r) {
            int q = mt * 16 + ((lane >> 4) << 2) + r;
            float iv = inv_[mt][r];
            #pragma unroll
            for (int nt = 0; nt < 2; ++nt) {
                int ch = (h << 5) + nt * 16 + (lane & 15);
                *reinterpret_cast<f16*>(LDSRAW + ((q * 512 + ch * 2) ^ ((q & 7) << 4))) = (f16)(o[mt][nt][r] * iv);
            }
        }
    __syncthreads();

    // fused proj: wave h computes output channels [32h, 32h+32)
    f32x4 pc[4][2];
    #pragma unroll
    for (int mt = 0; mt < 4; ++mt) { pc[mt][0] = fzero; pc[mt][1] = fzero; }
    #pragma unroll
    for (int ks = 0; ks < 8; ++ks) {
        f16x8 a[4], b[2];
        #pragma unroll
        for (int mt = 0; mt < 4; ++mt) {
            int q = mt * 16 + (lane & 15);
            a[mt] = *reinterpret_cast<const f16x8*>(LDSRAW + ((q * 512 + ks * 64 + ((lane >> 4) << 4)) ^ ((q & 7) << 4)));
        }
        #pragma unroll
        for (int nt = 0; nt < 2; ++nt)
            b[nt] = *reinterpret_cast<const f16x8*>(p_t + ((h << 5) + nt * 16 + (lane & 15)) * 256 + ks * 32 + ((lane >> 4) << 3));
        #pragma unroll
        for (int mt = 0; mt < 4; ++mt)
            #pragma unroll
            for (int nt = 0; nt < 2; ++nt)
                pc[mt][nt] = __builtin_amdgcn_mfma_f32_16x16x32_f16(a[mt], b[nt], pc[mt][nt], 0, 0, 0);
    }

    const int bb = bw >> 10;
    #pragma unroll
    for (int mt = 0; mt < 4; ++mt)
        #pragma unroll
        for (int r = 0; r < 4; ++r) {
            int q = mt * 16 + ((lane >> 4) << 2) + r;
            int i = ((wh << 3) + (q >> 3) + 4) & 255;   // roll(+4) un-partition
            int j = ((ww << 3) + (q & 7) + 4) & 255;
            long addr = (((long)bb * 256 + i) * 256 + j) * 256;
            #pragma unroll
            for (int nt = 0; nt < 2; ++nt) {
                int ch = (h << 5) + nt * 16 + (lane & 15);
                out[addr + ch] = pc[mt][nt][r] + proj_b[ch];
            }
        }
}

extern "C" void kernel_launch(void* const* d_in, const int* in_sizes, int n_in,
                              void* d_out, int out_size, void* d_ws, size_t ws_size,
                              hipStream_t stream) {
    const float* x      = (const float*)d_in[0];
    const float* qkv_w  = (const float*)d_in[1];
    const float* q_bias = (const float*)d_in[2];
    const float* v_bias = (const float*)d_in[3];
    const float* scale  = (const float*)d_in[4];
    const float* cpb_w1 = (const float*)d_in[5];
    const float* cpb_b1 = (const float*)d_in[6];
    const float* cpb_w2 = (const float*)d_in[7];
    const float* proj_w = (const float*)d_in[8];
    const float* proj_b = (const float*)d_in[9];
    float* out = (float*)d_out;

    char* ws = (char*)d_ws;
    float* biasfrag = (float*)(ws);                         // 128 KiB
    f16* w_t  = (f16*)(ws + 131072);                        // 384 KiB
    f16* p_t  = (f16*)(ws + 524288);                        // 128 KiB
    f16* qbuf = (f16*)(ws + (1u << 20));                    // 64 MiB
    f16* kbuf = (f16*)(ws + (1u << 20) + (1u << 26));       // 64 MiB
    f16* vtbuf = (f16*)(ws + (1u << 20) + 2u * (1u << 26)); // 64 MiB
    // requires ws_size >= ~193 MiB

    hipLaunchKernelGGL(k_prep, dim3(129), dim3(512), 0, stream,
                       cpb_w1, cpb_b1, cpb_w2, qkv_w, proj_w, biasfrag, w_t, p_t);
    hipLaunchKernelGGL(k_qkv, dim3(1024), dim3(512), 0, stream,
                       x, w_t, q_bias, v_bias, scale, qbuf, kbuf, vtbuf);
    hipLaunchKernelGGL(k_attn_proj, dim3(2048), dim3(512), 0, stream,
                       qbuf, kbuf, vtbuf, biasfrag, p_t, proj_b, out);
}